// Round 6
// baseline (4013.791 us; speedup 1.0000x reference)
//
#include <hip/hip_runtime.h>
#include <hip/hip_bf16.h>
#include <stdint.h>

typedef float f32x4 __attribute__((ext_vector_type(4)));
typedef int i32x4 __attribute__((ext_vector_type(4)));

// ---------------- async global -> LDS (16B/lane, wave-uniform LDS base) ----------------
__device__ __forceinline__ void gload_lds16(const void* g, void* l) {
    __builtin_amdgcn_global_load_lds(
        (const __attribute__((address_space(1))) unsigned int*)g,
        (__attribute__((address_space(3))) unsigned int*)l,
        16, 0, 0);
}

// ---------------- per-row activation quantization: f32 -> i8, qrow = amax/127 ----------------
__global__ __launch_bounds__(256) void quant_rows_kernel(
        const float* __restrict__ A, signed char* __restrict__ Aq,
        float* __restrict__ qrow, int K) {
    const long row = blockIdx.x;
    const float* a = A + row * (long)K;
    signed char* o = Aq + row * (long)K;
    const int tid = threadIdx.x;
    const int nch = K >> 2;                       // f32x4 chunks per row
    float amax = 0.f;
    for (int c = tid; c < nch; c += 256) {
        f32x4 v = ((const f32x4*)a)[c];
        amax = fmaxf(amax, fmaxf(fmaxf(fabsf(v[0]), fabsf(v[1])),
                                 fmaxf(fabsf(v[2]), fabsf(v[3]))));
    }
#pragma unroll
    for (int off = 32; off; off >>= 1)
        amax = fmaxf(amax, __shfl_xor(amax, off, 64));
    __shared__ float red[4];
    if ((tid & 63) == 0) red[tid >> 6] = amax;
    __syncthreads();
    amax = fmaxf(fmaxf(red[0], red[1]), fmaxf(red[2], red[3]));
    const float s = amax > 0.f ? 127.f / amax : 0.f;
    if (tid == 0) qrow[row] = amax > 0.f ? amax / 127.f : 0.f;
    for (int c = tid; c < nch; c += 256) {       // second sweep: row is L1/L2-hot
        f32x4 v = ((const f32x4*)a)[c];
        int r = 0;
#pragma unroll
        for (int i = 0; i < 4; ++i) {
            int q = (int)__builtin_rintf(v[i] * s);
            r |= (q & 0xff) << (8 * i);
        }
        ((int*)o)[c] = r;
    }
}

// ---------------- weight conversion: i32 (int8-range) -> i8, exact ----------------
__global__ __launch_bounds__(256) void cvt_i32_i8_kernel(
        const int* __restrict__ in, signed char* __restrict__ out, long n) {
    long base = ((long)blockIdx.x * 256 + threadIdx.x) * 16;
    long stride = (long)gridDim.x * 256 * 16;
    for (long i = base; i < n; i += stride) {
        i32x4 pk;
#pragma unroll
        for (int c = 0; c < 4; ++c) {
            i32x4 v = *(const i32x4*)(in + i + c * 4);
            pk[c] = (v[0] & 0xff) | ((v[1] & 0xff) << 8) |
                    ((v[2] & 0xff) << 16) | ((v[3] & 0xff) << 24);
        }
        *(i32x4*)(out + i) = pk;
    }
}

// =====================================================================
// 256x256 8-phase i8 GEMM (round-4 verified geometry, BK=64, 64 KiB LDS),
// mfma_i32_16x16x64_i8, now at 2 blocks/CU (__launch_bounds__(512,4)).
// C = (Aq*qrow[row]) * Wq^T * s[col] + b[col].
// 512 thr = 8 waves (2M x 4N).  LDS 64 KiB:
// region(buf,op,half) = buf*32768 + op*16384 + half*8192 BYTES,
// each region = 128 rows x 64 cols i8, row-major 64 B rows,
// swizzle: LDS[row][slot16B] holds global k-chunk slot ^ ((row>>1)&3).
// =====================================================================

// stage one half-tile (128 rows x 64 cols i8): ONE issue of 512 lanes x 16 B
__device__ __forceinline__ void stage_half(const signed char* __restrict__ G,
        long grow0, int K, int kcol0, signed char* lds_region, int tid) {
    const int row  = tid >> 2;                       // 0..127
    const int slot = tid & 3;                        // 16B slot within 64B row
    const int gcol = kcol0 + ((slot ^ ((row >> 1) & 3)) << 4);  // pre-swizzled source
    const int wid  = tid >> 6;
    gload_lds16(G + (grow0 + row) * (long)K + gcol,
                lds_region + wid * 1024);            // HW adds lane*16B
}

// A fragments 16x16x64: lane holds row (lane&15), k = (lane>>4)*16 + 0..15 (one b128)
template<int BUF, int MH>
__device__ __forceinline__ void readA(const signed char* smem, i32x4 (&fa)[4],
                                      int wr, int lane) {
    const signed char* rg = smem + BUF * 32768 + MH * 8192;
    const int fr = lane & 15, kg = lane >> 4;
#pragma unroll
    for (int ml = 0; ml < 4; ++ml) {
        const int lrow = wr * 16 + ml * 32 + fr;
        fa[ml] = *(const i32x4*)(rg + lrow * 64 + ((kg ^ ((lrow >> 1) & 3)) << 4));
    }
}

template<int BUF, int NH>
__device__ __forceinline__ void readB(const signed char* smem, i32x4 (&fb)[2],
                                      int wc, int lane) {
    const signed char* rg = smem + BUF * 32768 + 16384 + NH * 8192;
    const int fr = lane & 15, kg = lane >> 4;
#pragma unroll
    for (int nl = 0; nl < 2; ++nl) {
        const int lrow = wc * 16 + nl * 64 + fr;
        fb[nl] = *(const i32x4*)(rg + lrow * 64 + ((kg ^ ((lrow >> 1) & 3)) << 4));
    }
}

template<int MH, int NH>
__device__ __forceinline__ void mfmas(i32x4 (&acc)[8][4],
                                      const i32x4 (&fa)[4], const i32x4 (&fb)[2]) {
#pragma unroll
    for (int ml = 0; ml < 4; ++ml)
#pragma unroll
        for (int nl = 0; nl < 2; ++nl)
            acc[MH * 4 + ml][NH * 2 + nl] = __builtin_amdgcn_mfma_i32_16x16x64_i8(
                fa[ml], fb[nl], acc[MH * 4 + ml][NH * 2 + nl], 0, 0, 0);
}

#define SYNC_PRE()  { __builtin_amdgcn_s_barrier();                              \
                      asm volatile("s_waitcnt lgkmcnt(0)" ::: "memory");         \
                      __builtin_amdgcn_sched_barrier(0);                         \
                      __builtin_amdgcn_s_setprio(1); }
#define POST()      { __builtin_amdgcn_s_setprio(0); __builtin_amdgcn_s_barrier(); }
#define POST_V3()   { __builtin_amdgcn_s_setprio(0);                             \
                      asm volatile("s_waitcnt vmcnt(3)" ::: "memory");           \
                      __builtin_amdgcn_s_barrier(); }
#define POST_V0()   { __builtin_amdgcn_s_setprio(0);                             \
                      asm volatile("s_waitcnt vmcnt(0)" ::: "memory");           \
                      __builtin_amdgcn_s_barrier(); }

__global__ __launch_bounds__(512, 4) void gemm_i8_8phase(
        const signed char* __restrict__ A,      // [M][K] i8
        const signed char* __restrict__ W,      // [N][K] i8
        const float* __restrict__ qrow,         // [M] row dequant scale
        const float* __restrict__ scales,       // [N]
        const float* __restrict__ bias,         // [N]
        float* __restrict__ C,                  // [M][N]
        int M, int N, int K) {
    extern __shared__ signed char smem[];       // 65536 B

    const int tid  = threadIdx.x;
    const int wid  = tid >> 6;
    const int lane = tid & 63;
    const int wr = wid >> 2;     // 0..1
    const int wc = wid & 3;      // 0..3
    const int fr = lane & 15;
    const int fq = lane >> 4;

    const int nwg = gridDim.x;
    const int bid = blockIdx.x;
    const int swz = ((nwg & 7) == 0) ? ((bid & 7) * (nwg >> 3) + (bid >> 3)) : bid;
    const int tiles_n = N >> 8;
    const int tm = swz / tiles_n;
    const int tn = swz % tiles_n;
    const long arow = (long)tm * 256;
    const long brow = (long)tn * 256;

    i32x4 acc[8][4] = {};
    i32x4 fa[4], fb0[2], fb1[2];

    const int NT = K >> 6;       // K-tiles of 64; NT even, >= 4

#define STA(kt, h) stage_half(A, arow + (h) * 128, K, (kt) * 64, \
                              smem + ((kt) & 1) * 32768 + (h) * 8192, tid)
#define STB(kt, h) stage_half(W, brow + (h) * 128, K, (kt) * 64, \
                              smem + ((kt) & 1) * 32768 + 16384 + (h) * 8192, tid)

    // ---- prologue: 7 half-tile stages (tile0 full + tile1 minus A.h1)
    STA(0, 0); STB(0, 0); STA(0, 1); STB(0, 1);
    STA(1, 0); STB(1, 0); STB(1, 1);
    asm volatile("s_waitcnt vmcnt(3)" ::: "memory");   // tile0's 4 stages landed
    __builtin_amdgcn_s_barrier();

    // ---- main loop: iteration consumes tiles (2i)->buf0, (2i+1)->buf1
    for (int i = 0; i < (NT >> 1) - 1; ++i) {
        const int b = 2 * i + 1, c = 2 * i + 2, d = 2 * i + 3;
        // ph1 (mh0,nh0 of buf0)
        readA<0, 0>(smem, fa, wr, lane); readB<0, 0>(smem, fb0, wc, lane); STA(b, 1);
        SYNC_PRE(); mfmas<0, 0>(acc, fa, fb0); POST();
        // ph2 (mh0,nh1)
        readB<0, 1>(smem, fb1, wc, lane); STA(c, 0);
        SYNC_PRE(); mfmas<0, 1>(acc, fa, fb1); POST();
        // ph3 (mh1,nh0)
        readA<0, 1>(smem, fa, wr, lane); STB(c, 0);
        SYNC_PRE(); mfmas<1, 0>(acc, fa, fb0); POST();
        // ph4 (mh1,nh1) + fence: tile b fully landed before ph5 reads buf1
        STB(c, 1);
        SYNC_PRE(); mfmas<1, 1>(acc, fa, fb1); POST_V3();
        // ph5 (mh0,nh0 of buf1)
        readA<1, 0>(smem, fa, wr, lane); readB<1, 0>(smem, fb0, wc, lane); STA(c, 1);
        SYNC_PRE(); mfmas<0, 0>(acc, fa, fb0); POST();
        // ph6
        readB<1, 1>(smem, fb1, wc, lane); STA(d, 0);
        SYNC_PRE(); mfmas<0, 1>(acc, fa, fb1); POST();
        // ph7
        readA<1, 1>(smem, fa, wr, lane); STB(d, 0);
        SYNC_PRE(); mfmas<1, 0>(acc, fa, fb0); POST();
        // ph8 + fence: tile c fully landed before next-iter ph1 reads buf0
        STB(d, 1);
        SYNC_PRE(); mfmas<1, 1>(acc, fa, fb1); POST_V3();
    }

    // ---- epilogue iteration: tiles NT-2 (buf0), NT-1 (buf1); no further prefetch
    readA<0, 0>(smem, fa, wr, lane); readB<0, 0>(smem, fb0, wc, lane); STA(NT - 1, 1);
    SYNC_PRE(); mfmas<0, 0>(acc, fa, fb0); POST();
    readB<0, 1>(smem, fb1, wc, lane);
    SYNC_PRE(); mfmas<0, 1>(acc, fa, fb1); POST();
    readA<0, 1>(smem, fa, wr, lane);
    SYNC_PRE(); mfmas<1, 0>(acc, fa, fb0); POST();
    SYNC_PRE(); mfmas<1, 1>(acc, fa, fb1); POST_V0();   // drain: tile NT-1 fully landed
    readA<1, 0>(smem, fa, wr, lane); readB<1, 0>(smem, fb0, wc, lane);
    SYNC_PRE(); mfmas<0, 0>(acc, fa, fb0); POST();
    readB<1, 1>(smem, fb1, wc, lane);
    SYNC_PRE(); mfmas<0, 1>(acc, fa, fb1); POST();
    readA<1, 1>(smem, fa, wr, lane);
    SYNC_PRE(); mfmas<1, 0>(acc, fa, fb0); POST();
    SYNC_PRE(); mfmas<1, 1>(acc, fa, fb1);
    __builtin_amdgcn_s_setprio(0);

#undef STA
#undef STB

    // ---- dequant row scales: qr[m][j] for this thread's 32 output rows
    float qr[8][4];
#pragma unroll
    for (int mh = 0; mh < 2; ++mh)
#pragma unroll
        for (int ml = 0; ml < 4; ++ml) {
            const long row0 = arow + wr * 16 + mh * 128 + ml * 32 + fq * 4;
#pragma unroll
            for (int j = 0; j < 4; ++j)
                qr[mh * 4 + ml][j] = qrow[row0 + j];
        }

    // ---- C write: out = acc * qrow[row] * scales[col] + bias[col]
    // 16x16 C/D layout: col = lane&15, row = (lane>>4)*4 + reg
#pragma unroll
    for (int n = 0; n < 4; ++n) {
        const int col = tn * 256 + wc * 16 + n * 64 + fr;
        const float s = scales[col];
        const float bb = bias[col];
#pragma unroll
        for (int mh = 0; mh < 2; ++mh)
#pragma unroll
            for (int ml = 0; ml < 4; ++ml) {
                const int m = mh * 4 + ml;
                const long row0 = arow + wr * 16 + mh * 128 + ml * 32 + fq * 4;
#pragma unroll
                for (int j = 0; j < 4; ++j)
                    C[(row0 + j) * (long)N + col] =
                        (float)acc[m][n][j] * (qr[m][j] * s) + bb;
            }
    }
}

// ---------------- fallback: plain fp32 (odd shapes / tiny ws only) ----------------
__global__ __launch_bounds__(256) void gemm_fallback_kernel(
        const float* __restrict__ A, const int* __restrict__ W,
        const float* __restrict__ scales, const float* __restrict__ bias,
        float* __restrict__ C, int M, int N, int K) {
    __shared__ float As[64][16];
    __shared__ float Ws[64][16];
    const int tiles_n = N / 64;
    const int tm = blockIdx.x / tiles_n, tn = blockIdx.x % tiles_n;
    const int tid = threadIdx.x, tx = tid & 15, ty = tid >> 4;
    float acc[4][4] = {};
    for (int k0 = 0; k0 < K; k0 += 16) {
        __syncthreads();
#pragma unroll
        for (int i = 0; i < 4; ++i) {
            const int idx = tid + i * 256;
            const int r = idx >> 4, c = idx & 15;
            As[r][c] = A[(long)(tm * 64 + r) * K + k0 + c];
            Ws[r][c] = (float)W[(long)(tn * 64 + r) * K + k0 + c];
        }
        __syncthreads();
#pragma unroll
        for (int kk = 0; kk < 16; ++kk) {
            float a[4], w[4];
#pragma unroll
            for (int r = 0; r < 4; ++r) a[r] = As[ty * 4 + r][kk];
#pragma unroll
            for (int c = 0; c < 4; ++c) w[c] = Ws[tx * 4 + c][kk];
#pragma unroll
            for (int r = 0; r < 4; ++r)
#pragma unroll
                for (int c = 0; c < 4; ++c) acc[r][c] += a[r] * w[c];
        }
    }
#pragma unroll
    for (int r = 0; r < 4; ++r)
#pragma unroll
        for (int c = 0; c < 4; ++c) {
            const int col = tn * 64 + tx * 4 + c;
            C[(long)(tm * 64 + ty * 4 + r) * N + col] = acc[r][c] * scales[col] + bias[col];
        }
}

extern "C" void kernel_launch(void* const* d_in, const int* in_sizes, int n_in,
                              void* d_out, int out_size, void* d_ws, size_t ws_size,
                              hipStream_t stream) {
    const float* A32    = (const float*)d_in[0];
    const int*   Wq     = (const int*)d_in[1];
    const float* scales = (const float*)d_in[2];
    const float* bias   = (const float*)d_in[3];
    float* C = (float*)d_out;

    const long aElems = in_sizes[0];        // M*K
    const long wElems = in_sizes[1];        // N*K
    const int  N = in_sizes[2];
    const int  K = (int)(wElems / N);
    const int  M = (int)(aElems / K);

    const size_t need = (size_t)aElems + (size_t)wElems + (size_t)M * 4 + 64;
    const bool div256 = (M % 256 == 0) && (N % 256 == 0) && (K % 128 == 0) && (K >= 256);

    if (ws_size >= need && div256) {
        signed char* Aq  = (signed char*)d_ws;
        signed char* Wq8 = Aq + aElems;
        float* qrow = (float*)(Wq8 + wElems);
        quant_rows_kernel<<<M, 256, 0, stream>>>(A32, Aq, qrow, K);
        cvt_i32_i8_kernel<<<2048, 256, 0, stream>>>(Wq, Wq8, wElems);
        const int nwg = (M / 256) * (N / 256);
        gemm_i8_8phase<<<nwg, 512, 65536, stream>>>(Aq, Wq8, qrow, scales, bias, C, M, N, K);
    } else {
        const int nwg = (M / 64) * (N / 64);
        gemm_fallback_kernel<<<nwg, 256, 0, stream>>>(A32, Wq, scales, bias, C, M, N, K);
    }
}

// Round 7
// 482.838 us; speedup vs baseline: 8.3129x; 8.3129x over previous
//
#include <hip/hip_runtime.h>
#include <hip/hip_bf16.h>
#include <stdint.h>

typedef float f32x4 __attribute__((ext_vector_type(4)));
typedef int i32x4 __attribute__((ext_vector_type(4)));

// ---------------- async global -> LDS (16B/lane, wave-uniform LDS base) ----------------
__device__ __forceinline__ void gload_lds16(const signed char* g, signed char* l) {
    __builtin_amdgcn_global_load_lds(
        (const __attribute__((address_space(1))) unsigned int*)g,
        (__attribute__((address_space(3))) unsigned int*)l,
        16, 0, 0);
}

// ---------------- per-row activation quantization: f32 -> i8, qrow = amax/127 ----------------
__global__ __launch_bounds__(256) void quant_rows_kernel(
        const float* __restrict__ A, signed char* __restrict__ Aq,
        float* __restrict__ qrow, int K) {
    const long row = blockIdx.x;
    const float* a = A + row * (long)K;
    signed char* o = Aq + row * (long)K;
    const int tid = threadIdx.x;
    const int nch = K >> 2;                       // f32x4 chunks per row
    float amax = 0.f;
    for (int c = tid; c < nch; c += 256) {
        f32x4 v = ((const f32x4*)a)[c];
        amax = fmaxf(amax, fmaxf(fmaxf(fabsf(v[0]), fabsf(v[1])),
                                 fmaxf(fabsf(v[2]), fabsf(v[3]))));
    }
#pragma unroll
    for (int off = 32; off; off >>= 1)
        amax = fmaxf(amax, __shfl_xor(amax, off, 64));
    __shared__ float red[4];
    if ((tid & 63) == 0) red[tid >> 6] = amax;
    __syncthreads();
    amax = fmaxf(fmaxf(red[0], red[1]), fmaxf(red[2], red[3]));
    const float s = amax > 0.f ? 127.f / amax : 0.f;
    if (tid == 0) qrow[row] = amax > 0.f ? amax / 127.f : 0.f;
    for (int c = tid; c < nch; c += 256) {       // second sweep: row is L1/L2-hot
        f32x4 v = ((const f32x4*)a)[c];
        int r = 0;
#pragma unroll
        for (int i = 0; i < 4; ++i) {
            int q = (int)__builtin_rintf(v[i] * s);
            r |= (q & 0xff) << (8 * i);
        }
        ((int*)o)[c] = r;
    }
}

// ---------------- weight conversion: i32 (int8-range) -> i8, exact ----------------
__global__ __launch_bounds__(256) void cvt_i32_i8_kernel(
        const int* __restrict__ in, signed char* __restrict__ out, long n) {
    long base = ((long)blockIdx.x * 256 + threadIdx.x) * 16;
    long stride = (long)gridDim.x * 256 * 16;
    for (long i = base; i < n; i += stride) {
        i32x4 pk;
#pragma unroll
        for (int c = 0; c < 4; ++c) {
            i32x4 v = *(const i32x4*)(in + i + c * 4);
            pk[c] = (v[0] & 0xff) | ((v[1] & 0xff) << 8) |
                    ((v[2] & 0xff) << 16) | ((v[3] & 0xff) << 24);
        }
        *(i32x4*)(out + i) = pk;
    }
}

// =====================================================================
// 256x256 8-phase i8 GEMM, BK=64, software-pipelined fragment reads:
// phase = {barrier; lgkm0(prev reads); MFMA_k; reads_{k+1}; stage; [vmcnt]}.
// Single barrier per phase (hazard table verified: stage@j vs reads@j-2).
// LDS 64 KiB: region(buf,op,half) = buf*32768 + op*16384 + half*8192 B,
// each region = 128 rows x 64 cols i8, 64-B rows,
// swizzle: LDS[row][slot16B] holds global k-chunk slot ^ ((row>>1)&3).
// =====================================================================

template<int BUF, int MH>
__device__ __forceinline__ void readAf(const signed char* smem, i32x4 (&fa)[4],
                                       const int (&off)[4]) {
    const signed char* rg = smem + BUF * 32768 + MH * 8192;
#pragma unroll
    for (int ml = 0; ml < 4; ++ml)
        fa[ml] = *(const i32x4*)(rg + off[ml]);
}

template<int BUF, int NH>
__device__ __forceinline__ void readBf(const signed char* smem, i32x4 (&fb)[2],
                                       const int (&off)[2]) {
    const signed char* rg = smem + BUF * 32768 + 16384 + NH * 8192;
#pragma unroll
    for (int nl = 0; nl < 2; ++nl)
        fb[nl] = *(const i32x4*)(rg + off[nl]);
}

template<int MH, int NH>
__device__ __forceinline__ void mfmas(i32x4 (&acc)[8][4],
                                      const i32x4 (&fa)[4], const i32x4 (&fb)[2]) {
#pragma unroll
    for (int ml = 0; ml < 4; ++ml)
#pragma unroll
        for (int nl = 0; nl < 2; ++nl)
            acc[MH * 4 + ml][NH * 2 + nl] = __builtin_amdgcn_mfma_i32_16x16x64_i8(
                fa[ml], fb[nl], acc[MH * 4 + ml][NH * 2 + nl], 0, 0, 0);
}

#define BARw()  __builtin_amdgcn_s_barrier()
#define LG0()   { asm volatile("s_waitcnt lgkmcnt(0)" ::: "memory"); \
                  __builtin_amdgcn_sched_barrier(0); }
#define P1()    __builtin_amdgcn_s_setprio(1)
#define P0()    __builtin_amdgcn_s_setprio(0)
#define VM2()   asm volatile("s_waitcnt vmcnt(2)" ::: "memory")
#define VM0()   asm volatile("s_waitcnt vmcnt(0)" ::: "memory")

__global__ __launch_bounds__(512, 1) void gemm_i8_8phase(
        const signed char* __restrict__ A,      // [M][K] i8
        const signed char* __restrict__ W,      // [N][K] i8
        const float* __restrict__ qrow,         // [M] row dequant scale
        const float* __restrict__ scales,       // [N]
        const float* __restrict__ bias,         // [N]
        float* __restrict__ C,                  // [M][N]
        int M, int N, int K) {
    extern __shared__ signed char smem[];       // 65536 B

    const int tid  = threadIdx.x;
    const int lane = tid & 63;
    const int wid  = tid >> 6;
    const int wr = wid >> 2;     // 0..1
    const int wc = wid & 3;      // 0..3
    const int fr = lane & 15;
    const int fq = lane >> 4;
    const int kg = lane >> 4;

    const int nwg = gridDim.x;
    const int bid = blockIdx.x;
    const int swz = ((nwg & 7) == 0) ? ((bid & 7) * (nwg >> 3) + (bid >> 3)) : bid;
    const int tiles_n = N >> 8;
    const int tm = swz / tiles_n;
    const int tn = swz % tiles_n;
    const int arow = tm << 8;
    const int brow = tn << 8;

    // ---- thread-constant LDS read byte-offsets within a region
    int aRd[4], bRd[2];
#pragma unroll
    for (int ml = 0; ml < 4; ++ml) {
        const int lrow = wr * 16 + ml * 32 + fr;
        aRd[ml] = lrow * 64 + ((kg ^ ((lrow >> 1) & 3)) << 4);
    }
#pragma unroll
    for (int nl = 0; nl < 2; ++nl) {
        const int lrow = wc * 16 + nl * 64 + fr;
        bRd[nl] = lrow * 64 + ((kg ^ ((lrow >> 1) & 3)) << 4);
    }

    // ---- thread-constant stage offsets (32-bit, i8 elements == bytes)
    const int srow = tid >> 2;
    const int sswz = (((tid & 3) ^ ((srow >> 1) & 3)) << 4);   // pre-swizzled source col
    int aOff[2], wOff[2];
#pragma unroll
    for (int h = 0; h < 2; ++h) {
        aOff[h] = (arow + h * 128 + srow) * K + sswz;
        wOff[h] = (brow + h * 128 + srow) * K + sswz;
    }
    const int ldsSt = wid * 1024;

#define STA(kt, h) gload_lds16(A + aOff[h] + (kt) * 64, \
                               smem + ((kt) & 1) * 32768 + (h) * 8192 + ldsSt)
#define STB(kt, h) gload_lds16(W + wOff[h] + (kt) * 64, \
                               smem + ((kt) & 1) * 32768 + 16384 + (h) * 8192 + ldsSt)

    i32x4 acc[8][4] = {};
    i32x4 faA[4], faB[4], fb0[2], fb1[2];

    const int NT = K >> 6;       // K-tiles of 64; NT even, >= 4

    // ---- prologue: stage tile0 full + tile1 minus A.h1; pre-read ph1 frags
    STA(0, 0); STB(0, 0); STA(0, 1); STB(0, 1);
    STA(1, 0); STB(1, 0); STB(1, 1);
    asm volatile("s_waitcnt vmcnt(3)" ::: "memory");   // tile0's 4 stages landed
    BARw();
    readAf<0, 0>(smem, faA, aRd);
    readBf<0, 0>(smem, fb0, bRd);

    // ---- main loop: iteration consumes tiles (2i)->buf0, (2i+1)->buf1
    for (int i = 0; i < (NT >> 1) - 1; ++i) {
        const int b = 2 * i + 1, c = 2 * i + 2, d = 2 * i + 3;
        // ph1: MFMA(mh0,nh0 | buf0)
        BARw(); LG0(); P1(); mfmas<0, 0>(acc, faA, fb0); P0();
        readBf<0, 1>(smem, fb1, bRd); STA(b, 1);
        // ph2: MFMA(mh0,nh1)
        BARw(); LG0(); P1(); mfmas<0, 1>(acc, faA, fb1); P0();
        readAf<0, 1>(smem, faB, aRd); STA(c, 0);
        // ph3: MFMA(mh1,nh0); fence -> tile b (buf1) fully landed
        BARw(); LG0(); P1(); mfmas<1, 0>(acc, faB, fb0); P0();
        STB(c, 0); VM2();
        // ph4: MFMA(mh1,nh1); reads for buf1
        BARw(); P1(); mfmas<1, 1>(acc, faB, fb1); P0();
        readAf<1, 0>(smem, faA, aRd); readBf<1, 0>(smem, fb0, bRd); STB(c, 1);
        // ph5: MFMA(mh0,nh0 | buf1)
        BARw(); LG0(); P1(); mfmas<0, 0>(acc, faA, fb0); P0();
        readBf<1, 1>(smem, fb1, bRd); STA(c, 1);
        // ph6
        BARw(); LG0(); P1(); mfmas<0, 1>(acc, faA, fb1); P0();
        readAf<1, 1>(smem, faB, aRd); STA(d, 0);
        // ph7: fence -> tile c (buf0) fully landed
        BARw(); LG0(); P1(); mfmas<1, 0>(acc, faB, fb0); P0();
        STB(d, 0); VM2();
        // ph8: reads for next iter's buf0
        BARw(); P1(); mfmas<1, 1>(acc, faB, fb1); P0();
        readAf<0, 0>(smem, faA, aRd); readBf<0, 0>(smem, fb0, bRd); STB(d, 1);
    }

    // ---- epilogue: tiles NT-2 (buf0), NT-1 (buf1)
    // e1
    BARw(); LG0(); P1(); mfmas<0, 0>(acc, faA, fb0); P0();
    readBf<0, 1>(smem, fb1, bRd); STA(NT - 1, 1);
    // e2
    BARw(); LG0(); P1(); mfmas<0, 1>(acc, faA, fb1); P0();
    readAf<0, 1>(smem, faB, aRd);
    // e3: drain all stages (tile NT-1 fully landed)
    BARw(); LG0(); P1(); mfmas<1, 0>(acc, faB, fb0); P0();
    VM0();
    // e4
    BARw(); P1(); mfmas<1, 1>(acc, faB, fb1); P0();
    readAf<1, 0>(smem, faA, aRd); readBf<1, 0>(smem, fb0, bRd);
    // e5
    BARw(); LG0(); P1(); mfmas<0, 0>(acc, faA, fb0); P0();
    readBf<1, 1>(smem, fb1, bRd);
    // e6
    BARw(); LG0(); P1(); mfmas<0, 1>(acc, faA, fb1); P0();
    readAf<1, 1>(smem, faB, aRd);
    // e7
    BARw(); LG0(); P1(); mfmas<1, 0>(acc, faB, fb0); P0();
    // e8
    BARw(); P1(); mfmas<1, 1>(acc, faB, fb1); P0();

#undef STA
#undef STB

    // ---- dequant row scales for this thread's 32 output rows
    float qr[8][4];
#pragma unroll
    for (int mh = 0; mh < 2; ++mh)
#pragma unroll
        for (int ml = 0; ml < 4; ++ml) {
            const int row0 = arow + wr * 16 + mh * 128 + ml * 32 + fq * 4;
#pragma unroll
            for (int j = 0; j < 4; ++j)
                qr[mh * 4 + ml][j] = qrow[row0 + j];
        }

    // ---- C write: out = acc * qrow[row] * scales[col] + bias[col]
    // 16x16 C/D layout: col = lane&15, row = (lane>>4)*4 + reg
#pragma unroll
    for (int n = 0; n < 4; ++n) {
        const int col = tn * 256 + wc * 16 + n * 64 + fr;
        const float s = scales[col];
        const float bb = bias[col];
#pragma unroll
        for (int mh = 0; mh < 2; ++mh)
#pragma unroll
            for (int ml = 0; ml < 4; ++ml) {
                const int m = mh * 4 + ml;
                const int row0 = arow + wr * 16 + mh * 128 + ml * 32 + fq * 4;
#pragma unroll
                for (int j = 0; j < 4; ++j)
                    C[(long)(row0 + j) * N + col] =
                        (float)acc[m][n][j] * (qr[m][j] * s) + bb;
            }
    }
}

// ---------------- fallback: plain fp32 (odd shapes / tiny ws only) ----------------
__global__ __launch_bounds__(256) void gemm_fallback_kernel(
        const float* __restrict__ A, const int* __restrict__ W,
        const float* __restrict__ scales, const float* __restrict__ bias,
        float* __restrict__ C, int M, int N, int K) {
    __shared__ float As[64][16];
    __shared__ float Ws[64][16];
    const int tiles_n = N / 64;
    const int tm = blockIdx.x / tiles_n, tn = blockIdx.x % tiles_n;
    const int tid = threadIdx.x, tx = tid & 15, ty = tid >> 4;
    float acc[4][4] = {};
    for (int k0 = 0; k0 < K; k0 += 16) {
        __syncthreads();
#pragma unroll
        for (int i = 0; i < 4; ++i) {
            const int idx = tid + i * 256;
            const int r = idx >> 4, c = idx & 15;
            As[r][c] = A[(long)(tm * 64 + r) * K + k0 + c];
            Ws[r][c] = (float)W[(long)(tn * 64 + r) * K + k0 + c];
        }
        __syncthreads();
#pragma unroll
        for (int kk = 0; kk < 16; ++kk) {
            float a[4], w[4];
#pragma unroll
            for (int r = 0; r < 4; ++r) a[r] = As[ty * 4 + r][kk];
#pragma unroll
            for (int c = 0; c < 4; ++c) w[c] = Ws[tx * 4 + c][kk];
#pragma unroll
            for (int r = 0; r < 4; ++r)
#pragma unroll
                for (int c = 0; c < 4; ++c) acc[r][c] += a[r] * w[c];
        }
    }
#pragma unroll
    for (int r = 0; r < 4; ++r)
#pragma unroll
        for (int c = 0; c < 4; ++c) {
            const int col = tn * 64 + tx * 4 + c;
            C[(long)(tm * 64 + ty * 4 + r) * N + col] = acc[r][c] * scales[col] + bias[col];
        }
}

extern "C" void kernel_launch(void* const* d_in, const int* in_sizes, int n_in,
                              void* d_out, int out_size, void* d_ws, size_t ws_size,
                              hipStream_t stream) {
    const float* A32    = (const float*)d_in[0];
    const int*   Wq     = (const int*)d_in[1];
    const float* scales = (const float*)d_in[2];
    const float* bias   = (const float*)d_in[3];
    float* C = (float*)d_out;

    const long aElems = in_sizes[0];        // M*K
    const long wElems = in_sizes[1];        // N*K
    const int  N = in_sizes[2];
    const int  K = (int)(wElems / N);
    const int  M = (int)(aElems / K);

    const size_t need = (size_t)aElems + (size_t)wElems + (size_t)M * 4 + 64;
    const bool div256 = (M % 256 == 0) && (N % 256 == 0) && (K % 128 == 0) && (K >= 256) &&
                        ((long)M * K < 2000000000L) && ((long)N * K < 2000000000L);

    if (ws_size >= need && div256) {
        signed char* Aq  = (signed char*)d_ws;
        signed char* Wq8 = Aq + aElems;
        float* qrow = (float*)(Wq8 + wElems);
        quant_rows_kernel<<<M, 256, 0, stream>>>(A32, Aq, qrow, K);
        cvt_i32_i8_kernel<<<2048, 256, 0, stream>>>(Wq, Wq8, wElems);
        const int nwg = (M / 256) * (N / 256);
        gemm_i8_8phase<<<nwg, 512, 65536, stream>>>(Aq, Wq8, qrow, scales, bias, C, M, N, K);
    } else {
        const int nwg = (M / 64) * (N / 64);
        gemm_fallback_kernel<<<nwg, 256, 0, stream>>>(A32, Wq, scales, bias, C, M, N, K);
    }
}

// Round 8
// 482.484 us; speedup vs baseline: 8.3190x; 1.0007x over previous
//
#include <hip/hip_runtime.h>
#include <hip/hip_bf16.h>
#include <stdint.h>

typedef float f32x4 __attribute__((ext_vector_type(4)));
typedef int i32x4 __attribute__((ext_vector_type(4)));

// ---------------- async global -> LDS (16B/lane, wave-uniform LDS base) ----------------
__device__ __forceinline__ void gload_lds16(const signed char* g, signed char* l) {
    __builtin_amdgcn_global_load_lds(
        (const __attribute__((address_space(1))) unsigned int*)g,
        (__attribute__((address_space(3))) unsigned int*)l,
        16, 0, 0);
}

// ---------------- per-row activation quantization: f32 -> i8, qrow = amax/127 ----------------
__global__ __launch_bounds__(256) void quant_rows_kernel(
        const float* __restrict__ A, signed char* __restrict__ Aq,
        float* __restrict__ qrow, int K) {
    const long row = blockIdx.x;
    const float* a = A + row * (long)K;
    signed char* o = Aq + row * (long)K;
    const int tid = threadIdx.x;
    const int nch = K >> 2;                       // f32x4 chunks per row
    float amax = 0.f;
    for (int c = tid; c < nch; c += 256) {
        f32x4 v = ((const f32x4*)a)[c];
        amax = fmaxf(amax, fmaxf(fmaxf(fabsf(v[0]), fabsf(v[1])),
                                 fmaxf(fabsf(v[2]), fabsf(v[3]))));
    }
#pragma unroll
    for (int off = 32; off; off >>= 1)
        amax = fmaxf(amax, __shfl_xor(amax, off, 64));
    __shared__ float red[4];
    if ((tid & 63) == 0) red[tid >> 6] = amax;
    __syncthreads();
    amax = fmaxf(fmaxf(red[0], red[1]), fmaxf(red[2], red[3]));
    const float s = amax > 0.f ? 127.f / amax : 0.f;
    if (tid == 0) qrow[row] = amax > 0.f ? amax / 127.f : 0.f;
    for (int c = tid; c < nch; c += 256) {       // second sweep: row is L1/L2-hot
        f32x4 v = ((const f32x4*)a)[c];
        int r = 0;
#pragma unroll
        for (int i = 0; i < 4; ++i) {
            int q = (int)__builtin_rintf(v[i] * s);
            r |= (q & 0xff) << (8 * i);
        }
        ((int*)o)[c] = r;
    }
}

// ---------------- weight conversion: i32 (int8-range) -> i8, exact ----------------
__global__ __launch_bounds__(256) void cvt_i32_i8_kernel(
        const int* __restrict__ in, signed char* __restrict__ out, long n) {
    long base = ((long)blockIdx.x * 256 + threadIdx.x) * 16;
    long stride = (long)gridDim.x * 256 * 16;
    for (long i = base; i < n; i += stride) {
        i32x4 pk;
#pragma unroll
        for (int c = 0; c < 4; ++c) {
            i32x4 v = *(const i32x4*)(in + i + c * 4);
            pk[c] = (v[0] & 0xff) | ((v[1] & 0xff) << 8) |
                    ((v[2] & 0xff) << 16) | ((v[3] & 0xff) << 24);
        }
        *(i32x4*)(out + i) = pk;
    }
}

// =====================================================================
// 256x256 8-phase i8 GEMM, BK=64, overlap-pipelined:
// phase = {barrier; lgkm0(prev reads); reads_{k+1}; stage; MFMA_k; [vmcnt]}.
// Reads drain on LDS pipe concurrently with MFMA pipe.  Fence/epoch
// schedule identical to the race-verified round-4/7 table.
// LDS 64 KiB: region(buf,op,half) = buf*32768 + op*16384 + half*8192 B,
// each region = 128 rows x 64 cols i8, 64-B rows,
// swizzle: LDS[row][slot16B] holds global k-chunk slot ^ ((row>>1)&3).
// =====================================================================

template<int BUF, int MH>
__device__ __forceinline__ void readAf(const signed char* smem, i32x4 (&fa)[4],
                                       const int (&off)[4]) {
    const signed char* rg = smem + BUF * 32768 + MH * 8192;
#pragma unroll
    for (int ml = 0; ml < 4; ++ml)
        fa[ml] = *(const i32x4*)(rg + off[ml]);
}

template<int BUF, int NH>
__device__ __forceinline__ void readBf(const signed char* smem, i32x4 (&fb)[2],
                                       const int (&off)[2]) {
    const signed char* rg = smem + BUF * 32768 + 16384 + NH * 8192;
#pragma unroll
    for (int nl = 0; nl < 2; ++nl)
        fb[nl] = *(const i32x4*)(rg + off[nl]);
}

template<int MH, int NH>
__device__ __forceinline__ void mfmas(i32x4 (&acc)[8][4],
                                      const i32x4 (&fa)[4], const i32x4 (&fb)[2]) {
#pragma unroll
    for (int ml = 0; ml < 4; ++ml)
#pragma unroll
        for (int nl = 0; nl < 2; ++nl)
            acc[MH * 4 + ml][NH * 2 + nl] = __builtin_amdgcn_mfma_i32_16x16x64_i8(
                fa[ml], fb[nl], acc[MH * 4 + ml][NH * 2 + nl], 0, 0, 0);
}

#define BARw()  __builtin_amdgcn_s_barrier()
#define LG0()   { asm volatile("s_waitcnt lgkmcnt(0)" ::: "memory"); \
                  __builtin_amdgcn_sched_barrier(0); }
#define SB0()   __builtin_amdgcn_sched_barrier(0)
#define P1()    __builtin_amdgcn_s_setprio(1)
#define P0()    __builtin_amdgcn_s_setprio(0)
#define VM2()   asm volatile("s_waitcnt vmcnt(2)" ::: "memory")
#define VM0()   asm volatile("s_waitcnt vmcnt(0)" ::: "memory")

__global__ __launch_bounds__(512, 1) void gemm_i8_8phase(
        const signed char* __restrict__ A,      // [M][K] i8
        const signed char* __restrict__ W,      // [N][K] i8
        const float* __restrict__ qrow,         // [M] row dequant scale
        const float* __restrict__ scales,       // [N]
        const float* __restrict__ bias,         // [N]
        float* __restrict__ C,                  // [M][N]
        int M, int N, int K) {
    extern __shared__ signed char smem[];       // 65536 B

    const int tid  = threadIdx.x;
    const int lane = tid & 63;
    const int wid  = tid >> 6;
    const int wr = wid >> 2;     // 0..1
    const int wc = wid & 3;      // 0..3
    const int fr = lane & 15;
    const int fq = lane >> 4;
    const int kg = lane >> 4;

    const int nwg = gridDim.x;
    const int bid = blockIdx.x;
    const int swz = ((nwg & 7) == 0) ? ((bid & 7) * (nwg >> 3) + (bid >> 3)) : bid;
    const int tiles_n = N >> 8;
    const int tm = swz / tiles_n;
    const int tn = swz % tiles_n;
    const int arow = tm << 8;
    const int brow = tn << 8;

    // ---- thread-constant LDS read byte-offsets within a region
    int aRd[4], bRd[2];
#pragma unroll
    for (int ml = 0; ml < 4; ++ml) {
        const int lrow = wr * 16 + ml * 32 + fr;
        aRd[ml] = lrow * 64 + ((kg ^ ((lrow >> 1) & 3)) << 4);
    }
#pragma unroll
    for (int nl = 0; nl < 2; ++nl) {
        const int lrow = wc * 16 + nl * 64 + fr;
        bRd[nl] = lrow * 64 + ((kg ^ ((lrow >> 1) & 3)) << 4);
    }

    // ---- thread-constant stage offsets (32-bit, i8 elements == bytes)
    const int srow = tid >> 2;
    const int sswz = (((tid & 3) ^ ((srow >> 1) & 3)) << 4);   // pre-swizzled source col
    int aOff[2], wOff[2];
#pragma unroll
    for (int h = 0; h < 2; ++h) {
        aOff[h] = (arow + h * 128 + srow) * K + sswz;
        wOff[h] = (brow + h * 128 + srow) * K + sswz;
    }
    const int ldsSt = wid * 1024;

#define STA(kt, h) gload_lds16(A + aOff[h] + (kt) * 64, \
                               smem + ((kt) & 1) * 32768 + (h) * 8192 + ldsSt)
#define STB(kt, h) gload_lds16(W + wOff[h] + (kt) * 64, \
                               smem + ((kt) & 1) * 32768 + 16384 + (h) * 8192 + ldsSt)

    i32x4 acc[8][4] = {};
    i32x4 faA[4], faB[4], fb0[2], fb1[2];

    const int NT = K >> 6;       // K-tiles of 64; NT even, >= 4

    // ---- prologue: stage tile0 full + tile1 minus A.h1; pre-read ph1 frags
    STA(0, 0); STB(0, 0); STA(0, 1); STB(0, 1);
    STA(1, 0); STB(1, 0); STB(1, 1);
    asm volatile("s_waitcnt vmcnt(3)" ::: "memory");   // tile0's 4 stages landed
    BARw();
    readAf<0, 0>(smem, faA, aRd);
    readBf<0, 0>(smem, fb0, bRd);

    // ---- main loop: iteration consumes tiles (2i)->buf0, (2i+1)->buf1
    for (int i = 0; i < (NT >> 1) - 1; ++i) {
        const int b = 2 * i + 1, c = 2 * i + 2, d = 2 * i + 3;
        // ph1: reads for ph2 ahead of MFMA(mh0,nh0 | buf0)
        BARw(); LG0();
        readBf<0, 1>(smem, fb1, bRd); STA(b, 1); SB0();
        P1(); mfmas<0, 0>(acc, faA, fb0); P0();
        // ph2
        BARw(); LG0();
        readAf<0, 1>(smem, faB, aRd); STA(c, 0); SB0();
        P1(); mfmas<0, 1>(acc, faA, fb1); P0();
        // ph3: no reads (buf1 not fenced yet); fence at end
        BARw(); LG0();
        STB(c, 0); SB0();
        P1(); mfmas<1, 0>(acc, faB, fb0); P0();
        VM2();                                   // tile b (buf1) fully landed
        // ph4: reads for buf1
        BARw();
        readAf<1, 0>(smem, faA, aRd); readBf<1, 0>(smem, fb0, bRd); STB(c, 1); SB0();
        P1(); mfmas<1, 1>(acc, faB, fb1); P0();
        // ph5
        BARw(); LG0();
        readBf<1, 1>(smem, fb1, bRd); STA(c, 1); SB0();
        P1(); mfmas<0, 0>(acc, faA, fb0); P0();
        // ph6
        BARw(); LG0();
        readAf<1, 1>(smem, faB, aRd); STA(d, 0); SB0();
        P1(); mfmas<0, 1>(acc, faA, fb1); P0();
        // ph7: fence at end -> tile c (buf0) fully landed
        BARw(); LG0();
        STB(d, 0); SB0();
        P1(); mfmas<1, 0>(acc, faB, fb0); P0();
        VM2();
        // ph8: reads for next iter's buf0
        BARw();
        readAf<0, 0>(smem, faA, aRd); readBf<0, 0>(smem, fb0, bRd); STB(d, 1); SB0();
        P1(); mfmas<1, 1>(acc, faB, fb1); P0();
    }

    // ---- epilogue: tiles NT-2 (buf0), NT-1 (buf1)
    // e1
    BARw(); LG0();
    readBf<0, 1>(smem, fb1, bRd); STA(NT - 1, 1); SB0();
    P1(); mfmas<0, 0>(acc, faA, fb0); P0();
    // e2
    BARw(); LG0();
    readAf<0, 1>(smem, faB, aRd); SB0();
    P1(); mfmas<0, 1>(acc, faA, fb1); P0();
    // e3: drain all stages (tile NT-1 fully landed)
    BARw(); LG0();
    P1(); mfmas<1, 0>(acc, faB, fb0); P0();
    VM0();
    // e4
    BARw();
    readAf<1, 0>(smem, faA, aRd); readBf<1, 0>(smem, fb0, bRd); SB0();
    P1(); mfmas<1, 1>(acc, faB, fb1); P0();
    // e5
    BARw(); LG0();
    readBf<1, 1>(smem, fb1, bRd); SB0();
    P1(); mfmas<0, 0>(acc, faA, fb0); P0();
    // e6
    BARw(); LG0();
    readAf<1, 1>(smem, faB, aRd); SB0();
    P1(); mfmas<0, 1>(acc, faA, fb1); P0();
    // e7
    BARw(); LG0();
    P1(); mfmas<1, 0>(acc, faB, fb0); P0();
    // e8
    BARw();
    P1(); mfmas<1, 1>(acc, faB, fb1); P0();

#undef STA
#undef STB

    // ---- dequant row scales for this thread's 32 output rows
    float qr[8][4];
#pragma unroll
    for (int mh = 0; mh < 2; ++mh)
#pragma unroll
        for (int ml = 0; ml < 4; ++ml) {
            const int row0 = arow + wr * 16 + mh * 128 + ml * 32 + fq * 4;
#pragma unroll
            for (int j = 0; j < 4; ++j)
                qr[mh * 4 + ml][j] = qrow[row0 + j];
        }

    // ---- C write: out = acc * qrow[row] * scales[col] + bias[col]
    // 16x16 C/D layout: col = lane&15, row = (lane>>4)*4 + reg
#pragma unroll
    for (int n = 0; n < 4; ++n) {
        const int col = tn * 256 + wc * 16 + n * 64 + fr;
        const float s = scales[col];
        const float bb = bias[col];
#pragma unroll
        for (int mh = 0; mh < 2; ++mh)
#pragma unroll
            for (int ml = 0; ml < 4; ++ml) {
                const int m = mh * 4 + ml;
                const int row0 = arow + wr * 16 + mh * 128 + ml * 32 + fq * 4;
#pragma unroll
                for (int j = 0; j < 4; ++j)
                    C[(long)(row0 + j) * N + col] =
                        (float)acc[m][n][j] * (qr[m][j] * s) + bb;
            }
    }
}

// ---------------- fallback: plain fp32 (odd shapes / tiny ws only) ----------------
__global__ __launch_bounds__(256) void gemm_fallback_kernel(
        const float* __restrict__ A, const int* __restrict__ W,
        const float* __restrict__ scales, const float* __restrict__ bias,
        float* __restrict__ C, int M, int N, int K) {
    __shared__ float As[64][16];
    __shared__ float Ws[64][16];
    const int tiles_n = N / 64;
    const int tm = blockIdx.x / tiles_n, tn = blockIdx.x % tiles_n;
    const int tid = threadIdx.x, tx = tid & 15, ty = tid >> 4;
    float acc[4][4] = {};
    for (int k0 = 0; k0 < K; k0 += 16) {
        __syncthreads();
#pragma unroll
        for (int i = 0; i < 4; ++i) {
            const int idx = tid + i * 256;
            const int r = idx >> 4, c = idx & 15;
            As[r][c] = A[(long)(tm * 64 + r) * K + k0 + c];
            Ws[r][c] = (float)W[(long)(tn * 64 + r) * K + k0 + c];
        }
        __syncthreads();
#pragma unroll
        for (int kk = 0; kk < 16; ++kk) {
            float a[4], w[4];
#pragma unroll
            for (int r = 0; r < 4; ++r) a[r] = As[ty * 4 + r][kk];
#pragma unroll
            for (int c = 0; c < 4; ++c) w[c] = Ws[tx * 4 + c][kk];
#pragma unroll
            for (int r = 0; r < 4; ++r)
#pragma unroll
                for (int c = 0; c < 4; ++c) acc[r][c] += a[r] * w[c];
        }
    }
#pragma unroll
    for (int r = 0; r < 4; ++r)
#pragma unroll
        for (int c = 0; c < 4; ++c) {
            const int col = tn * 64 + tx * 4 + c;
            C[(long)(tm * 64 + ty * 4 + r) * N + col] = acc[r][c] * scales[col] + bias[col];
        }
}

extern "C" void kernel_launch(void* const* d_in, const int* in_sizes, int n_in,
                              void* d_out, int out_size, void* d_ws, size_t ws_size,
                              hipStream_t stream) {
    const float* A32    = (const float*)d_in[0];
    const int*   Wq     = (const int*)d_in[1];
    const float* scales = (const float*)d_in[2];
    const float* bias   = (const float*)d_in[3];
    float* C = (float*)d_out;

    const long aElems = in_sizes[0];        // M*K
    const long wElems = in_sizes[1];        // N*K
    const int  N = in_sizes[2];
    const int  K = (int)(wElems / N);
    const int  M = (int)(aElems / K);

    const size_t need = (size_t)aElems + (size_t)wElems + (size_t)M * 4 + 64;
    const bool div256 = (M % 256 == 0) && (N % 256 == 0) && (K % 128 == 0) && (K >= 256) &&
                        ((long)M * K < 2000000000L) && ((long)N * K < 2000000000L);

    if (ws_size >= need && div256) {
        signed char* Aq  = (signed char*)d_ws;
        signed char* Wq8 = Aq + aElems;
        float* qrow = (float*)(Wq8 + wElems);
        quant_rows_kernel<<<M, 256, 0, stream>>>(A32, Aq, qrow, K);
        cvt_i32_i8_kernel<<<2048, 256, 0, stream>>>(Wq, Wq8, wElems);
        const int nwg = (M / 256) * (N / 256);
        gemm_i8_8phase<<<nwg, 512, 65536, stream>>>(Aq, Wq8, qrow, scales, bias, C, M, N, K);
    } else {
        const int nwg = (M / 64) * (N / 64);
        gemm_fallback_kernel<<<nwg, 256, 0, stream>>>(A32, Wq, scales, bias, C, M, N, K);
    }
}